// Round 3
// baseline (183.808 us; speedup 1.0000x reference)
//
#include <hip/hip_runtime.h>
#include <hip/hip_cooperative_groups.h>
#include <math.h>

namespace cg = cooperative_groups;

// Sizes: E=256, R=16, F=64.
// LeakyReLU(a=0.2): lrelu(x) = 0.6x + 0.4|x|;  s>0 => lrelu(s*c*h) = s*(0.6*c*h + 0.4*|c|*|h|)
// att[j,k,f] = 0.6*c*P + 0.4*|c|*Q, c=h[j,f]*r[k,f], P=sum_i s[i,j,k]h[i,f], Q with |h|.

__device__ __forceinline__ float eluf(float x) { return x > 0.f ? x : expm1f(x); }

__global__ __launch_bounds__(256) void mega(
    const float* __restrict__ h, const float* __restrict__ r,
    const float* __restrict__ adj, const float* __restrict__ w,
    const float* __restrict__ bias, float* __restrict__ out,
    float* __restrict__ s, float* __restrict__ att, float* __restrict__ aR,
    float* __restrict__ lin, float* __restrict__ M, float* __restrict__ Sinv) {
  cg::grid_group grid = cg::this_grid();
  __shared__ float hl[256 * 64];   // 64 KB  h staged [i][f]
  __shared__ float sl[256 * 16];   // 16 KB  s[:,j,:] staged [i][k]
  __shared__ float rl[16 * 64];    // 4 KB   r staged
  __shared__ float attl[16 * 68];  // padded att tile [k][f]
  __shared__ float red[256];

  const int b = blockIdx.x;
  const int t = threadIdx.x;
  const int lane = t & 63;
  const int wv = t >> 6;

  // ================= P1: s[i,j,k] = softmax_j(adj[i,j,k]); block=i, thread=j
  {
    float v[16];
    const float4* a4 = (const float4*)(adj + b * 4096 + t * 16);
    float4 x0 = a4[0], x1 = a4[1], x2 = a4[2], x3 = a4[3];
    v[0]=x0.x; v[1]=x0.y; v[2]=x0.z; v[3]=x0.w;
    v[4]=x1.x; v[5]=x1.y; v[6]=x1.z; v[7]=x1.w;
    v[8]=x2.x; v[9]=x2.y; v[10]=x2.z; v[11]=x2.w;
    v[12]=x3.x; v[13]=x3.y; v[14]=x3.z; v[15]=x3.w;
    float m[16];
    #pragma unroll
    for (int k=0;k<16;++k) m[k]=v[k];
    #pragma unroll
    for (int off=1; off<64; off<<=1)
      #pragma unroll
      for (int k=0;k<16;++k) m[k] = fmaxf(m[k], __shfl_xor(m[k], off, 64));
    if (lane == 0) {
      #pragma unroll
      for (int k=0;k<16;++k) red[wv*16+k] = m[k];
    }
    __syncthreads();
    float sum[16];
    #pragma unroll
    for (int k=0;k<16;++k) {
      const float mk = fmaxf(fmaxf(red[k], red[16+k]), fmaxf(red[32+k], red[48+k]));
      v[k] = __expf(v[k] - mk);
      sum[k] = v[k];
    }
    #pragma unroll
    for (int off=1; off<64; off<<=1)
      #pragma unroll
      for (int k=0;k<16;++k) sum[k] += __shfl_xor(sum[k], off, 64);
    __syncthreads();
    if (lane == 0) {
      #pragma unroll
      for (int k=0;k<16;++k) red[wv*16+k] = sum[k];
    }
    __syncthreads();
    #pragma unroll
    for (int k=0;k<16;++k) {
      const float sk = red[k]+red[16+k]+red[32+k]+red[48+k];
      v[k] *= (1.f / sk);
    }
    float4* so4 = (float4*)(s + b*4096 + t*16);
    so4[0] = make_float4(v[0],v[1],v[2],v[3]);
    so4[1] = make_float4(v[4],v[5],v[6],v[7]);
    so4[2] = make_float4(v[8],v[9],v[10],v[11]);
    so4[3] = make_float4(v[12],v[13],v[14],v[15]);
  }
  grid.sync();

  // ================= P2: block=j, contraction + row softmax + aR + lin
  {
    const int j = b;
    float4* hl4 = (float4*)hl;
    const float4* h4 = (const float4*)h;
    #pragma unroll
    for (int q=0;q<16;++q) hl4[q*256+t] = h4[q*256+t];
    ((float4*)rl)[t] = ((const float4*)r)[t];
    float4* sl4 = (float4*)sl;
    const float4* s4c = (const float4*)s;
    #pragma unroll
    for (int q=0;q<4;++q) {
      const int c = q*256+t;                        // c = i*4 + kq
      sl4[c] = s4c[(c>>2)*1024 + j*4 + (c&3)];
    }
    __syncthreads();
    const int kg = t>>6, ig=(t>>4)&3, fg=t&15;
    float p[4][4] = {};
    float qa[4][4] = {};
    const int ibase = ig*64;
    #pragma unroll 8
    for (int ii=0; ii<64; ++ii) {
      const int i = ibase + ii;
      const float4 hv = *(const float4*)&hl[i*64 + fg*4];
      const float4 sv = *(const float4*)&sl[i*16 + kg*4];
      const float hvv[4] = {hv.x,hv.y,hv.z,hv.w};
      const float hav[4] = {fabsf(hv.x),fabsf(hv.y),fabsf(hv.z),fabsf(hv.w)};
      const float svv[4] = {sv.x,sv.y,sv.z,sv.w};
      #pragma unroll
      for (int kk=0;kk<4;++kk)
        #pragma unroll
        for (int ff=0;ff<4;++ff) {
          p[kk][ff]  = fmaf(svv[kk], hvv[ff], p[kk][ff]);
          qa[kk][ff] = fmaf(svv[kk], hav[ff], qa[kk][ff]);
        }
    }
    // reduce over ig via lane bits 4-5 (no LDS round-trip)
    #pragma unroll
    for (int kk=0;kk<4;++kk)
      #pragma unroll
      for (int ff=0;ff<4;++ff) {
        float pv = p[kk][ff];
        pv += __shfl_xor(pv, 16, 64);
        pv += __shfl_xor(pv, 32, 64);
        float qv = qa[kk][ff];
        qv += __shfl_xor(qv, 16, 64);
        qv += __shfl_xor(qv, 32, 64);
        if (ig == 0) {
          const int k = kg*4+kk, f = fg*4+ff;
          const float c = hl[j*64+f] * rl[k*64+f];
          attl[k*68+f] = 0.6f*c*pv + 0.4f*fabsf(c)*qv;
        }
      }
    __syncthreads();
    // att tile -> global (coalesced)
    #pragma unroll
    for (int q=0;q<4;++q) {
      const int kf = q*256 + t;
      att[j*1024 + kf] = attl[(kf>>6)*68 + (kf&63)];
    }
    // row softmax over k (f = lane), each wave stores 4 k's
    float av[16];
    #pragma unroll
    for (int k=0;k<16;++k) av[k] = attl[k*68 + lane];
    float mr = av[0];
    #pragma unroll
    for (int k=1;k<16;++k) mr = fmaxf(mr, av[k]);
    float ssum = 0.f;
    #pragma unroll
    for (int k=0;k<16;++k) ssum += __expf(av[k]-mr);
    const float inv = 1.f/ssum;
    const float wf = w[lane];
    const float bb = bias[0];
    #pragma unroll
    for (int mq=0; mq<4; ++mq) {
      const int k = wv*4 + mq;                       // runtime k -> read LDS, not reg array
      const float a = __expf(attl[k*68 + lane] - mr) * inv;
      aR[j*1024 + k*64 + lane] = a;
      float vsum = a * wf;
      #pragma unroll
      for (int off=1; off<64; off<<=1) vsum += __shfl_xor(vsum, off, 64);
      if (lane == 0) lin[j*16 + k] = vsum + bb;
    }
  }
  grid.sync();

  // ================= P3: column stats (M,Sinv), r_prime, alpha
  {
    const int c = t & 3;
    const int kf = b*4 + c;
    const int er = t >> 2;
    float av[4], rv[4];
    #pragma unroll
    for (int q=0;q<4;++q) {
      const int e = er + (q<<6);
      av[q] = att[e*1024 + kf];
      rv[q] = aR[e*1024 + kf];
    }
    float m = fmaxf(fmaxf(av[0],av[1]), fmaxf(av[2],av[3]));
    #pragma unroll
    for (int off=4; off<64; off<<=1) m = fmaxf(m, __shfl_xor(m, off, 64));
    if (lane < 4) red[wv*4 + c] = m;
    __syncthreads();
    const float mc = fmaxf(fmaxf(red[c], red[4+c]), fmaxf(red[8+c], red[12+c]));
    float es = __expf(av[0]-mc)+__expf(av[1]-mc)+__expf(av[2]-mc)+__expf(av[3]-mc);
    float rs = rv[0]+rv[1]+rv[2]+rv[3];
    #pragma unroll
    for (int off=4; off<64; off<<=1) {
      es += __shfl_xor(es, off, 64);
      rs += __shfl_xor(rs, off, 64);
    }
    __syncthreads();
    if (lane < 4) { red[wv*8 + c] = es; red[wv*8 + 4 + c] = rs; }
    __syncthreads();
    if (t < 4) {
      const int kf2 = b*4 + t;                       // c == t here
      const float S  = red[t] + red[8+t] + red[16+t] + red[24+t];
      const float RS = red[4+t] + red[12+t] + red[20+t] + red[28+t];
      M[kf2] = mc;
      Sinv[kf2] = 1.f/S;
      out[16384 + kf2] = eluf(r[kf2]*RS);
    }
  }
  if (b < 16) {  // alpha row b = softmax(lin[b*256 .. +256))
    __syncthreads();
    const float lv = lin[b*256 + t];
    float m2 = lv;
    #pragma unroll
    for (int off=1; off<64; off<<=1) m2 = fmaxf(m2, __shfl_xor(m2, off, 64));
    if (lane == 0) red[wv] = m2;
    __syncthreads();
    m2 = fmaxf(fmaxf(red[0],red[1]), fmaxf(red[2],red[3]));
    const float ex = __expf(lv - m2);
    float ss = ex;
    #pragma unroll
    for (int off=1; off<64; off<<=1) ss += __shfl_xor(ss, off, 64);
    __syncthreads();
    if (lane == 0) red[wv] = ss;
    __syncthreads();
    ss = red[0]+red[1]+red[2]+red[3];
    out[17408 + b*256 + t] = ex * (1.f/ss);
  }
  grid.sync();

  // ================= P4: h_prime; block=e
  {
    const int e = b;
    const int f = lane;
    float ssum = 0.f;
    #pragma unroll
    for (int kk=0;kk<4;++kk) {
      const int kf = (wv*4+kk)*64 + f;
      ssum += __expf(att[e*1024 + kf] - M[kf]) * Sinv[kf];
    }
    red[wv*64 + f] = ssum;
    __syncthreads();
    if (wv == 0) {
      const float tot = red[f] + red[64+f] + red[128+f] + red[192+f];
      out[e*64 + f] = eluf(h[e*64 + f] * tot);
    }
  }
}

extern "C" void kernel_launch(void* const* d_in, const int* in_sizes, int n_in,
                              void* d_out, int out_size, void* d_ws, size_t ws_size,
                              hipStream_t stream) {
  (void)in_sizes; (void)n_in; (void)out_size; (void)ws_size;
  const float* h   = (const float*)d_in[0];   // (256,64)
  const float* r   = (const float*)d_in[1];   // (16,64)
  const float* adj = (const float*)d_in[2];   // (256,256,16)
  const float* w   = (const float*)d_in[3];   // (1,64)
  const float* bi  = (const float*)d_in[4];   // (1,)
  float* out = (float*)d_out;                 // 16384 + 1024 + 4096

  float* ws   = (float*)d_ws;
  float* s    = ws;                 // 1,048,576 f32
  float* att  = ws + 1048576;       // 262,144 f32
  float* aR   = ws + 1310720;       // 262,144 f32
  float* lin  = ws + 1572864;       // 4,096 f32
  float* M    = ws + 1576960;       // 1,024 f32
  float* Sinv = ws + 1577984;       // 1,024 f32

  void* args[] = {(void*)&h, (void*)&r, (void*)&adj, (void*)&w, (void*)&bi,
                  (void*)&out, (void*)&s, (void*)&att, (void*)&aR, (void*)&lin,
                  (void*)&M, (void*)&Sinv};
  hipLaunchCooperativeKernel((const void*)mega, dim3(256), dim3(256), args, 0, stream);
}

// Round 4
// 87.948 us; speedup vs baseline: 2.0900x; 2.0900x over previous
//
#include <hip/hip_runtime.h>
#include <math.h>

// E=256, R=16, F=64.
// lrelu(a=0.2): lrelu(x)=0.6x+0.4|x|; softmax s>0 => lrelu(s*c*h)=s*(0.6*c*h+0.4*|c|*|h|)
// att[j,k,f] = 0.6*c*P + 0.4*|c|*Q, c=h[j,f]*r[k,f], P=sum_i s[i,j,k]h[i,f], Q with |h|.

__device__ __forceinline__ float eluf(float x) { return x > 0.f ? x : expm1f(x); }

// ---------------------------------------------------------------------------
// K1: s[i,j,k] = softmax_j(adj[i,j,k]). block=i (256), thread=j (256).
// Register-resident row, shfl-butterfly reductions. LDS: 256 B.
// ---------------------------------------------------------------------------
__global__ __launch_bounds__(256) void k1_softmax(const float* __restrict__ adj,
                                                  float* __restrict__ s) {
  __shared__ float red[64];
  const int b = blockIdx.x, t = threadIdx.x;
  const int lane = t & 63, wv = t >> 6;
  float v[16];
  const float4* a4 = (const float4*)(adj + b * 4096 + t * 16);
  float4 x0 = a4[0], x1 = a4[1], x2 = a4[2], x3 = a4[3];
  v[0]=x0.x; v[1]=x0.y; v[2]=x0.z; v[3]=x0.w;
  v[4]=x1.x; v[5]=x1.y; v[6]=x1.z; v[7]=x1.w;
  v[8]=x2.x; v[9]=x2.y; v[10]=x2.z; v[11]=x2.w;
  v[12]=x3.x; v[13]=x3.y; v[14]=x3.z; v[15]=x3.w;
  float m[16];
  #pragma unroll
  for (int k=0;k<16;++k) m[k]=v[k];
  #pragma unroll
  for (int off=1; off<64; off<<=1)
    #pragma unroll
    for (int k=0;k<16;++k) m[k] = fmaxf(m[k], __shfl_xor(m[k], off, 64));
  if (lane == 0) {
    #pragma unroll
    for (int k=0;k<16;++k) red[wv*16+k] = m[k];
  }
  __syncthreads();
  float sum[16];
  #pragma unroll
  for (int k=0;k<16;++k) {
    const float mk = fmaxf(fmaxf(red[k], red[16+k]), fmaxf(red[32+k], red[48+k]));
    v[k] = __expf(v[k] - mk);
    sum[k] = v[k];
  }
  #pragma unroll
  for (int off=1; off<64; off<<=1)
    #pragma unroll
    for (int k=0;k<16;++k) sum[k] += __shfl_xor(sum[k], off, 64);
  __syncthreads();
  if (lane == 0) {
    #pragma unroll
    for (int k=0;k<16;++k) red[wv*16+k] = sum[k];
  }
  __syncthreads();
  #pragma unroll
  for (int k=0;k<16;++k) {
    const float sk = red[k]+red[16+k]+red[32+k]+red[48+k];
    v[k] *= (1.f / sk);
  }
  float4* so4 = (float4*)(s + b*4096 + t*16);
  so4[0] = make_float4(v[0],v[1],v[2],v[3]);
  so4[1] = make_float4(v[4],v[5],v[6],v[7]);
  so4[2] = make_float4(v[8],v[9],v[10],v[11]);
  so4[3] = make_float4(v[12],v[13],v[14],v[15]);
}

// ---------------------------------------------------------------------------
// K2: per j (256 blocks, 1024 threads = 16 waves):
//   att[j,k,f]; then row-softmax over k -> aR, lin.
// t = [kg:2][igH:2][igL:2][fg:4]; ig = igH*4+igL owns 16 i's.
// ---------------------------------------------------------------------------
__global__ __launch_bounds__(1024) void k2_contract(const float* __restrict__ h,
                                                    const float* __restrict__ r,
                                                    const float* __restrict__ s,
                                                    const float* __restrict__ w,
                                                    const float* __restrict__ bias,
                                                    float* __restrict__ att,
                                                    float* __restrict__ aR,
                                                    float* __restrict__ lin) {
  __shared__ float hl[256 * 64];        // 64 KB
  __shared__ float redp[4 * 16 * 68];   // 17 KB
  __shared__ float redq[4 * 16 * 68];   // 17 KB
  __shared__ float attl[16 * 68];       // 4.3 KB
  const int j = blockIdx.x, t = threadIdx.x;
  const int lane = t & 63, wv = t >> 6;

  float4* hl4 = (float4*)hl;
  const float4* h4 = (const float4*)h;
  #pragma unroll
  for (int q=0;q<4;++q) hl4[q*1024+t] = h4[q*1024+t];
  __syncthreads();

  const int kg = t >> 8, igH = (t >> 6) & 3, igL = (t >> 4) & 3, fg = t & 15;
  const int ig = igH*4 + igL;
  float p[4][4] = {};
  float qa[4][4] = {};
  const float* sjb = s + j*16 + kg*4;
  #pragma unroll 8
  for (int ii=0; ii<16; ++ii) {
    const int i = ig*16 + ii;
    const float4 sv = *(const float4*)(sjb + (size_t)i*4096);
    const float4 hv = *(const float4*)&hl[i*64 + fg*4];
    const float hvv[4] = {hv.x,hv.y,hv.z,hv.w};
    const float hav[4] = {fabsf(hv.x),fabsf(hv.y),fabsf(hv.z),fabsf(hv.w)};
    const float svv[4] = {sv.x,sv.y,sv.z,sv.w};
    #pragma unroll
    for (int kk=0;kk<4;++kk)
      #pragma unroll
      for (int ff=0;ff<4;++ff) {
        p[kk][ff]  = fmaf(svv[kk], hvv[ff], p[kk][ff]);
        qa[kk][ff] = fmaf(svv[kk], hav[ff], qa[kk][ff]);
      }
  }
  // reduce igL (lane bits 4-5)
  #pragma unroll
  for (int kk=0;kk<4;++kk)
    #pragma unroll
    for (int ff=0;ff<4;++ff) {
      p[kk][ff]  += __shfl_xor(p[kk][ff], 16, 64);
      p[kk][ff]  += __shfl_xor(p[kk][ff], 32, 64);
      qa[kk][ff] += __shfl_xor(qa[kk][ff], 16, 64);
      qa[kk][ff] += __shfl_xor(qa[kk][ff], 32, 64);
    }
  if (igL == 0) {
    #pragma unroll
    for (int kk=0;kk<4;++kk) {
      const int row = igH*16 + kg*4 + kk;
      *(float4*)&redp[row*68 + fg*4] = make_float4(p[kk][0],p[kk][1],p[kk][2],p[kk][3]);
      *(float4*)&redq[row*68 + fg*4] = make_float4(qa[kk][0],qa[kk][1],qa[kk][2],qa[kk][3]);
    }
  }
  __syncthreads();
  // finalize: thread t -> (k,f)
  {
    const int k = t >> 6, f = t & 63;
    const int o = k*68 + f;
    const float pv = redp[o] + redp[1088+o] + redp[2176+o] + redp[3264+o];
    const float qv = redq[o] + redq[1088+o] + redq[2176+o] + redq[3264+o];
    const float c = hl[j*64+f] * r[k*64+f];
    const float av = 0.6f*c*pv + 0.4f*fabsf(c)*qv;
    attl[o] = av;
    att[j*1024 + t] = av;       // t == k*64+f, coalesced
  }
  __syncthreads();
  // row softmax over k (wave wv owns k=wv; f=lane)
  {
    const int f = lane;
    float mr = attl[f];
    #pragma unroll
    for (int k=1;k<16;++k) mr = fmaxf(mr, attl[k*68+f]);
    float ssum = 0.f;
    #pragma unroll
    for (int k=0;k<16;++k) ssum += __expf(attl[k*68+f]-mr);
    const float a = __expf(attl[wv*68+f]-mr) * (1.f/ssum);
    aR[j*1024 + wv*64 + f] = a;
    float vs = a * w[f];
    #pragma unroll
    for (int off=1; off<64; off<<=1) vs += __shfl_xor(vs, off, 64);
    if (f == 0) lin[j*16 + wv] = vs + bias[0];
  }
}

// ---------------------------------------------------------------------------
// K3: column stats over e. 64 blocks x 256 thr; block b owns kf = b*16..+16.
// t = [eg:4][kfo:4]; thread reduces e = q*16+eg, q=0..15.
// ---------------------------------------------------------------------------
__global__ __launch_bounds__(256) void k3_colstats(const float* __restrict__ att,
                                                   const float* __restrict__ aR,
                                                   const float* __restrict__ r,
                                                   float* __restrict__ M,
                                                   float* __restrict__ Sinv,
                                                   float* __restrict__ out) {
  __shared__ float redm[4][16], reds[4][16], redr[4][16];
  const int b = blockIdx.x, t = threadIdx.x;
  const int lane = t & 63, wv = t >> 6;
  const int kfo = t & 15, eg = t >> 4;
  const int kf = b*16 + kfo;
  float av[16], rv[16];
  #pragma unroll
  for (int q=0;q<16;++q) {
    const int e = q*16 + eg;
    av[q] = att[e*1024 + kf];
    rv[q] = aR[e*1024 + kf];
  }
  float m = av[0];
  #pragma unroll
  for (int q=1;q<16;++q) m = fmaxf(m, av[q]);
  m = fmaxf(m, __shfl_xor(m, 16, 64));
  m = fmaxf(m, __shfl_xor(m, 32, 64));
  if (lane < 16) redm[wv][kfo] = m;
  __syncthreads();
  const float mc = fmaxf(fmaxf(redm[0][kfo], redm[1][kfo]),
                         fmaxf(redm[2][kfo], redm[3][kfo]));
  float es = 0.f, rs = 0.f;
  #pragma unroll
  for (int q=0;q<16;++q) { es += __expf(av[q]-mc); rs += rv[q]; }
  es += __shfl_xor(es, 16, 64); es += __shfl_xor(es, 32, 64);
  rs += __shfl_xor(rs, 16, 64); rs += __shfl_xor(rs, 32, 64);
  if (lane < 16) { reds[wv][kfo] = es; redr[wv][kfo] = rs; }
  __syncthreads();
  if (t < 16) {
    const int kf2 = b*16 + t;
    const float mt = fmaxf(fmaxf(redm[0][t], redm[1][t]),
                           fmaxf(redm[2][t], redm[3][t]));
    const float S  = reds[0][t] + reds[1][t] + reds[2][t] + reds[3][t];
    const float RS = redr[0][t] + redr[1][t] + redr[2][t] + redr[3][t];
    M[kf2] = mt;
    Sinv[kf2] = 1.f/S;
    out[16384 + kf2] = eluf(r[kf2] * RS);
  }
}

// ---------------------------------------------------------------------------
// K4: blocks 0..255: h_prime row e=b (64 thr = f).
//     blocks 256..271: alpha row a=b-256 (softmax of 256 contiguous lin).
// ---------------------------------------------------------------------------
__global__ __launch_bounds__(64) void k4_final(const float* __restrict__ att,
                                               const float* __restrict__ lin,
                                               const float* __restrict__ h,
                                               const float* __restrict__ M,
                                               const float* __restrict__ Sinv,
                                               float* __restrict__ out) {
  const int b = blockIdx.x, t = threadIdx.x;
  if (b < 256) {
    const int e = b, f = t;
    float ssum = 0.f;
    #pragma unroll
    for (int k=0;k<16;++k) {
      const int kf = k*64 + f;
      ssum += __expf(att[e*1024 + kf] - M[kf]) * Sinv[kf];
    }
    out[e*64 + f] = eluf(h[e*64 + f] * ssum);
  } else {
    const int a = b - 256;
    float v[4];
    #pragma unroll
    for (int q=0;q<4;++q) v[q] = lin[a*256 + q*64 + t];
    float m2 = fmaxf(fmaxf(v[0],v[1]), fmaxf(v[2],v[3]));
    #pragma unroll
    for (int off=1; off<64; off<<=1) m2 = fmaxf(m2, __shfl_xor(m2, off, 64));
    float ex[4]; float ss = 0.f;
    #pragma unroll
    for (int q=0;q<4;++q) { ex[q] = __expf(v[q]-m2); ss += ex[q]; }
    #pragma unroll
    for (int off=1; off<64; off<<=1) ss += __shfl_xor(ss, off, 64);
    const float inv = 1.f/ss;
    #pragma unroll
    for (int q=0;q<4;++q) out[17408 + a*256 + q*64 + t] = ex[q]*inv;
  }
}

extern "C" void kernel_launch(void* const* d_in, const int* in_sizes, int n_in,
                              void* d_out, int out_size, void* d_ws, size_t ws_size,
                              hipStream_t stream) {
  (void)in_sizes; (void)n_in; (void)out_size; (void)ws_size;
  const float* h   = (const float*)d_in[0];   // (256,64)
  const float* r   = (const float*)d_in[1];   // (16,64)
  const float* adj = (const float*)d_in[2];   // (256,256,16)
  const float* w   = (const float*)d_in[3];   // (1,64)
  const float* bi  = (const float*)d_in[4];   // (1,)
  float* out = (float*)d_out;

  float* ws   = (float*)d_ws;
  float* s    = ws;                 // 1,048,576 f32
  float* att  = ws + 1048576;       // 262,144 f32
  float* aR   = ws + 1310720;       // 262,144 f32
  float* lin  = ws + 1572864;       // 4,096 f32
  float* M    = ws + 1576960;       // 1,024 f32
  float* Sinv = ws + 1577984;       // 1,024 f32

  hipLaunchKernelGGL(k1_softmax,   dim3(256), dim3(256),  0, stream, adj, s);
  hipLaunchKernelGGL(k2_contract,  dim3(256), dim3(1024), 0, stream, h, r, s, w, bi, att, aR, lin);
  hipLaunchKernelGGL(k3_colstats,  dim3(64),  dim3(256),  0, stream, att, aR, r, M, Sinv, out);
  hipLaunchKernelGGL(k4_final,     dim3(272), dim3(64),   0, stream, att, lin, h, M, Sinv, out);
}